// Round 5
// baseline (734.460 us; speedup 1.0000x reference)
//
#include <hip/hip_runtime.h>
#include <math.h>

#define BB 32
#define TT 48
#define NN 360
#define HH 100
#define DD 64
#define NC 2
#define G4 400
#define GRID_A 2048
#define XPROJ_BLOCKS 384    // 1536 bt-rows / 4 rows per block

__device__ __forceinline__ float sigmoid_fast(float x) {
    return 1.f / (1.f + __expf(-x));
}
__device__ __forceinline__ float tanh_fast(float x) {
    float ax = fabsf(x);
    float e = __expf(-2.f * ax);
    float t = (1.f - e) / (1.f + e);
    return copysignf(t, x);
}
__device__ __forceinline__ float dot4(float4 a, float4 b) {
    return a.x*b.x + a.y*b.y + a.z*b.z + a.w*b.w;
}
__device__ __forceinline__ float bcast_lane(float v, int l) {
    return __int_as_float(__builtin_amdgcn_readlane(__float_as_int(v), l));
}

// ---------------- K_A: fused transpose + GCN + xproj (one grid barrier) ----------------
// Phase 0: transpose W_ih [400,360] into pair-interleaved Wt2:
//          Wt2[n*400 + 2*(j%200) + j/200] = W_ih[j*360+n]
// Phase 1: gout[r] = relu(x[r,:]·w + b)  (grid-stride, 4 rows per wave-iter)
// Barrier: blocks >= XPROJ_BLOCKS arrive and exit; blocks < XPROJ_BLOCKS wait.
// Phase 2: xproj[bt,j] = gout[bt,:]·W_ih[j,:] + bias. No LDS: g rows are
//          uniform-address global float4 loads (1 line/wave-inst, L2-hot);
//          each thread covers cols (tid, tid+200) via one float2 of Wt2.
__global__ __launch_bounds__(256, 4) void fusedA_kernel(const float* __restrict__ x,
                                                        const float* __restrict__ w_gcn,
                                                        const float* __restrict__ bptr,
                                                        const float* __restrict__ W_ih,
                                                        const float* __restrict__ b_ih,
                                                        const float* __restrict__ b_hh,
                                                        float* __restrict__ gout,
                                                        float* __restrict__ Wt2,
                                                        float* __restrict__ xproj,
                                                        unsigned* __restrict__ bar) {
    __shared__ __align__(16) float4 w4[90];
    int tid = threadIdx.x;
    // ---- phase 0: transpose (one element per thread, coalesced read) ----
    {
        int idx = blockIdx.x * 256 + tid;
        if (idx < NN * G4) {
            int j = idx / NN, n = idx % NN;
            Wt2[n * G4 + 2 * (j % 200) + (j / 200)] = W_ih[idx];
        }
    }
    if (tid < 90) w4[tid] = ((const float4*)w_gcn)[tid];
    __syncthreads();
    // ---- phase 1: GCN ----
    {
        float b = bptr[0];
        int lane = tid & 63;
        int wv = tid >> 6;
        const int nquads = BB * TT * NN / 4;    // 138240
        const int stride = 4 * GRID_A;
        for (int q = blockIdx.x * 4 + wv; q < nquads; q += stride) {
            int row0 = 4 * q;
            const float4* x0 = (const float4*)(x + (size_t)(row0 + 0) * NN);
            const float4* x1 = (const float4*)(x + (size_t)(row0 + 1) * NN);
            const float4* x2 = (const float4*)(x + (size_t)(row0 + 2) * NN);
            const float4* x3 = (const float4*)(x + (size_t)(row0 + 3) * NN);
            float4 a0 = x0[lane];
            float4 a1 = x1[lane];
            float4 a2 = x2[lane];
            float4 a3 = x3[lane];
            float4 wa = w4[lane];
            float p0 = dot4(a0, wa);
            float p1 = dot4(a1, wa);
            float p2 = dot4(a2, wa);
            float p3 = dot4(a3, wa);
            if (lane < 26) {                     // 90 = 64 + 26
                float4 b0 = x0[lane + 64];
                float4 b1 = x1[lane + 64];
                float4 b2 = x2[lane + 64];
                float4 b3 = x3[lane + 64];
                float4 wb = w4[lane + 64];
                p0 += dot4(b0, wb);
                p1 += dot4(b1, wb);
                p2 += dot4(b2, wb);
                p3 += dot4(b3, wb);
            }
            #pragma unroll
            for (int off = 32; off; off >>= 1) {
                p0 += __shfl_down(p0, off, 64);
                p1 += __shfl_down(p1, off, 64);
                p2 += __shfl_down(p2, off, 64);
                p3 += __shfl_down(p3, off, 64);
            }
            if (lane == 0) {
                float4 r;
                r.x = fmaxf(p0 + b, 0.f);
                r.y = fmaxf(p1 + b, 0.f);
                r.z = fmaxf(p2 + b, 0.f);
                r.w = fmaxf(p3 + b, 0.f);
                ((float4*)gout)[q] = r;
            }
        }
    }
    // ---- grid barrier (release) ----
    __syncthreads();
    __threadfence();
    if (tid == 0) atomicAdd(bar, 1u);
    if (blockIdx.x >= XPROJ_BLOCKS) return;       // non-waiters free their CU slot
    if (tid == 0) {
        while (atomicAdd(bar, 0u) < (unsigned)GRID_A) __builtin_amdgcn_s_sleep(8);
    }
    __syncthreads();
    __threadfence();                              // acquire
    // ---- phase 2: xproj ----
    if (tid < 200) {
        int r0 = blockIdx.x * 4;
        float acc00 = 0.f, acc01 = 0.f, acc10 = 0.f, acc11 = 0.f;
        float acc20 = 0.f, acc21 = 0.f, acc30 = 0.f, acc31 = 0.f;
        const float* g0p = gout + (size_t)(r0 + 0) * NN;
        const float* g1p = gout + (size_t)(r0 + 1) * NN;
        const float* g2p = gout + (size_t)(r0 + 2) * NN;
        const float* g3p = gout + (size_t)(r0 + 3) * NN;
        const float* wp = Wt2 + 2 * tid;
        for (int n = 0; n < NN; n += 4) {
            float4 g0 = *(const float4*)(g0p + n);
            float4 g1 = *(const float4*)(g1p + n);
            float4 g2 = *(const float4*)(g2p + n);
            float4 g3 = *(const float4*)(g3p + n);
            float2 wA = *(const float2*)(wp + (n + 0) * G4);
            float2 wB = *(const float2*)(wp + (n + 1) * G4);
            float2 wC = *(const float2*)(wp + (n + 2) * G4);
            float2 wD = *(const float2*)(wp + (n + 3) * G4);
            acc00 += g0.x*wA.x + g0.y*wB.x + g0.z*wC.x + g0.w*wD.x;
            acc01 += g0.x*wA.y + g0.y*wB.y + g0.z*wC.y + g0.w*wD.y;
            acc10 += g1.x*wA.x + g1.y*wB.x + g1.z*wC.x + g1.w*wD.x;
            acc11 += g1.x*wA.y + g1.y*wB.y + g1.z*wC.y + g1.w*wD.y;
            acc20 += g2.x*wA.x + g2.y*wB.x + g2.z*wC.x + g2.w*wD.x;
            acc21 += g2.x*wA.y + g2.y*wB.y + g2.z*wC.y + g2.w*wD.y;
            acc30 += g3.x*wA.x + g3.y*wB.x + g3.z*wC.x + g3.w*wD.x;
            acc31 += g3.x*wA.y + g3.y*wB.y + g3.z*wC.y + g3.w*wD.y;
        }
        float bias0 = b_ih[tid] + b_hh[tid];
        float bias1 = b_ih[tid + 200] + b_hh[tid + 200];
        xproj[(size_t)(r0 + 0) * G4 + tid]       = acc00 + bias0;
        xproj[(size_t)(r0 + 0) * G4 + tid + 200] = acc01 + bias1;
        xproj[(size_t)(r0 + 1) * G4 + tid]       = acc10 + bias0;
        xproj[(size_t)(r0 + 1) * G4 + tid + 200] = acc11 + bias1;
        xproj[(size_t)(r0 + 2) * G4 + tid]       = acc20 + bias0;
        xproj[(size_t)(r0 + 2) * G4 + tid + 200] = acc21 + bias1;
        xproj[(size_t)(r0 + 3) * G4 + tid]       = acc30 + bias0;
        xproj[(size_t)(r0 + 3) * G4 + tid + 200] = acc31 + bias1;
    }
}

// ---------------- K_B: fused LSTM + MIL attention + classifier (unchanged R4) ----------------
__global__ __launch_bounds__(448) void lstm_attn_kernel(const float* __restrict__ xproj,
                                                        const float* __restrict__ Whh,
                                                        const float* __restrict__ wa1,
                                                        const float* __restrict__ ba1,
                                                        const float* __restrict__ wa2,
                                                        const float* __restrict__ ba2,
                                                        const float* __restrict__ wc,
                                                        const float* __restrict__ bc,
                                                        float* __restrict__ out) {
    __shared__ __align__(16) float ho[TT * HH];    // 19.2 KB
    __shared__ __align__(16) float h_lds[128];     // 100 used; 100..127 stay 0
    __shared__ float gates[G4];
    __shared__ float sc[TT];
    __shared__ float p[TT];
    __shared__ float M[HH];
    int b = blockIdx.x;
    int tid = threadIdx.x;
    int lane = tid & 63;
    float wr[HH];
    if (tid < G4) {
        #pragma unroll
        for (int k = 0; k < HH; k++) wr[k] = Whh[tid * HH + k];
    }
    float c = 0.f;
    if (tid < 128) h_lds[tid] = 0.f;
    float xp = (tid < G4) ? xproj[(size_t)(b * TT) * G4 + tid] : 0.f;
    __syncthreads();
    for (int t = 0; t < TT; t++) {
        float xp_next = (tid < G4 && t + 1 < TT)
                      ? xproj[(size_t)(b * TT + t + 1) * G4 + tid] : 0.f;
        float ha = h_lds[lane];
        float hb = h_lds[64 + lane];
        if (tid < G4) {
            float s0 = 0.f, s1 = 0.f, s2 = 0.f, s3 = 0.f;
            #pragma unroll
            for (int k = 0; k < 64; k += 4) {
                s0 += bcast_lane(ha, k+0) * wr[k+0];
                s1 += bcast_lane(ha, k+1) * wr[k+1];
                s2 += bcast_lane(ha, k+2) * wr[k+2];
                s3 += bcast_lane(ha, k+3) * wr[k+3];
            }
            #pragma unroll
            for (int k = 64; k < 100; k += 4) {
                s0 += bcast_lane(hb, k-64) * wr[k+0];
                s1 += bcast_lane(hb, k-63) * wr[k+1];
                s2 += bcast_lane(hb, k-62) * wr[k+2];
                s3 += bcast_lane(hb, k-61) * wr[k+3];
            }
            gates[tid] = xp + (s0 + s1) + (s2 + s3);
        }
        __syncthreads();
        if (tid < HH) {
            float ig = sigmoid_fast(gates[tid]);
            float fg = sigmoid_fast(gates[tid + HH]);
            float gg = tanh_fast(gates[tid + 2*HH]);
            float og = sigmoid_fast(gates[tid + 3*HH]);
            c = fg * c + ig * gg;
            float hh = og * tanh_fast(c);
            h_lds[tid] = hh;
            ho[t * HH + tid] = hh;
        }
        xp = xp_next;
        __syncthreads();
    }
    // ---- MIL attention ----
    int wave = tid >> 6;
    for (int t = wave; t < TT; t += 7) {
        float a = 0.f;
        if (lane < DD) {
            float s = ba1[lane];
            #pragma unroll
            for (int h2 = 0; h2 < HH; h2 += 4) {
                float4 h4v = *(const float4*)&ho[t*HH + h2];
                s += wa1[lane*HH + h2+0]*h4v.x + wa1[lane*HH + h2+1]*h4v.y
                   + wa1[lane*HH + h2+2]*h4v.z + wa1[lane*HH + h2+3]*h4v.w;
            }
            a = tanh_fast(s) * wa2[lane];
        }
        #pragma unroll
        for (int off = 32; off; off >>= 1) a += __shfl_down(a, off, 64);
        if (lane == 0) sc[t] = a + ba2[0];
    }
    __syncthreads();
    if (tid < 64) {
        float v = (lane < TT) ? sc[lane] : -1e30f;
        if (lane < TT) out[BB*NC + b*TT + lane] = v;      // Att (pre-softmax logits)
        float m = v;
        #pragma unroll
        for (int off = 32; off; off >>= 1) m = fmaxf(m, __shfl_xor(m, off, 64));
        float e = (lane < TT) ? __expf(v - m) : 0.f;
        float s = e;
        #pragma unroll
        for (int off = 32; off; off >>= 1) s += __shfl_xor(s, off, 64);
        if (lane < TT) p[lane] = e / s;
    }
    __syncthreads();
    if (tid < HH) {
        float m = 0.f;
        #pragma unroll
        for (int t = 0; t < TT; t++) m += p[t] * ho[t*HH + tid];
        M[tid] = m;
    }
    __syncthreads();
    if (tid == 0) {
        float l0 = bc[0], l1 = bc[1];
        for (int h2 = 0; h2 < HH; h2++) { l0 += M[h2]*wc[h2]; l1 += M[h2]*wc[HH + h2]; }
        float mx = fmaxf(l0, l1);
        float e0 = __expf(l0 - mx), e1 = __expf(l1 - mx);
        float s = e0 + e1;
        out[b*NC + 0] = e0 / s;
        out[b*NC + 1] = e1 / s;
    }
}

extern "C" void kernel_launch(void* const* d_in, const int* in_sizes, int n_in,
                              void* d_out, int out_size, void* d_ws, size_t ws_size,
                              hipStream_t stream) {
    const float* x     = (const float*)d_in[0];
    const float* w_gcn = (const float*)d_in[1];
    const float* b_gcn = (const float*)d_in[2];
    const float* W_ih  = (const float*)d_in[3];
    const float* W_hh  = (const float*)d_in[4];
    const float* b_ih  = (const float*)d_in[5];
    const float* b_hh  = (const float*)d_in[6];
    const float* wa1   = (const float*)d_in[7];
    const float* ba1   = (const float*)d_in[8];
    const float* wa2   = (const float*)d_in[9];
    const float* ba2   = (const float*)d_in[10];
    const float* wc    = (const float*)d_in[11];
    const float* bc    = (const float*)d_in[12];
    float* out = (float*)d_out;
    float* ws  = (float*)d_ws;

    float* gout  = ws;                       // 552960 floats
    float* Wt2   = gout + 552960;            // 144000 floats
    float* xproj = Wt2 + 144000;             // 614400 floats
    unsigned* bar = (unsigned*)((char*)d_ws + (8u << 20));  // barrier counter @ 8 MB

    hipMemsetAsync(bar, 0, 64, stream);
    fusedA_kernel<<<GRID_A, 256, 0, stream>>>(x, w_gcn, b_gcn, W_ih, b_ih, b_hh,
                                              gout, Wt2, xproj, bar);
    lstm_attn_kernel<<<BB, 448, 0, stream>>>(xproj, W_hh, wa1, ba1, wa2, ba2, wc, bc, out);
}

// Round 8
// 222.828 us; speedup vs baseline: 3.2961x; 3.2961x over previous
//
#include <hip/hip_runtime.h>
#include <math.h>

#define BB 32
#define TT 48
#define NN 360
#define HH 100
#define DD 64
#define NC 2
#define G4 400

typedef float vf4 __attribute__((ext_vector_type(4)));

__device__ __forceinline__ float sigmoid_fast(float x) {
    return 1.f / (1.f + __expf(-x));
}
__device__ __forceinline__ float tanh_fast(float x) {
    float ax = fabsf(x);
    float e = __expf(-2.f * ax);
    float t = (1.f - e) / (1.f + e);
    return copysignf(t, x);
}
__device__ __forceinline__ float dot4v(vf4 a, float4 b) {
    return a.x*b.x + a.y*b.y + a.z*b.z + a.w*b.w;
}
__device__ __forceinline__ float bcast_lane(float v, int l) {
    return __int_as_float(__builtin_amdgcn_readlane(__float_as_int(v), l));
}
__device__ __forceinline__ vf4 ntload4(const float* p) {
    return __builtin_nontemporal_load((const vf4*)p);
}

// ---------------- K1: GCN row reduction, 4 rows per wave-iteration ----------------
__global__ __launch_bounds__(256) void gcn_kernel(const float* __restrict__ x,
                                                  const float* __restrict__ w,
                                                  const float* __restrict__ bptr,
                                                  float* __restrict__ gout, int nquads) {
    __shared__ __align__(16) float4 w4[90];
    int tid = threadIdx.x;
    if (tid < 90) w4[tid] = ((const float4*)w)[tid];
    __syncthreads();
    float b = bptr[0];
    int lane = tid & 63;
    int wv = tid >> 6;                       // 0..3
    int stride = 4 * gridDim.x;
    for (int q = blockIdx.x * 4 + wv; q < nquads; q += stride) {
        int row0 = 4 * q;
        const float* x0 = x + (size_t)(row0 + 0) * NN;
        const float* x1 = x + (size_t)(row0 + 1) * NN;
        const float* x2 = x + (size_t)(row0 + 2) * NN;
        const float* x3 = x + (size_t)(row0 + 3) * NN;
        vf4 a0 = ntload4(x0 + 4*lane);
        vf4 a1 = ntload4(x1 + 4*lane);
        vf4 a2 = ntload4(x2 + 4*lane);
        vf4 a3 = ntload4(x3 + 4*lane);
        float4 wa = w4[lane];
        float p0 = dot4v(a0, wa);
        float p1 = dot4v(a1, wa);
        float p2 = dot4v(a2, wa);
        float p3 = dot4v(a3, wa);
        if (lane < 26) {                     // 90 = 64 + 26
            vf4 b0 = ntload4(x0 + 4*(lane + 64));
            vf4 b1 = ntload4(x1 + 4*(lane + 64));
            vf4 b2 = ntload4(x2 + 4*(lane + 64));
            vf4 b3 = ntload4(x3 + 4*(lane + 64));
            float4 wb = w4[lane + 64];
            p0 += dot4v(b0, wb);
            p1 += dot4v(b1, wb);
            p2 += dot4v(b2, wb);
            p3 += dot4v(b3, wb);
        }
        #pragma unroll
        for (int off = 32; off; off >>= 1) {
            p0 += __shfl_down(p0, off, 64);
            p1 += __shfl_down(p1, off, 64);
            p2 += __shfl_down(p2, off, 64);
            p3 += __shfl_down(p3, off, 64);
        }
        if (lane == 0) {
            float4 r;
            r.x = fmaxf(p0 + b, 0.f);
            r.y = fmaxf(p1 + b, 0.f);
            r.z = fmaxf(p2 + b, 0.f);
            r.w = fmaxf(p3 + b, 0.f);
            ((float4*)gout)[q] = r;
        }
    }
}

// ---------------- K2a: transpose W_ih [400,360] -> pair-interleaved Wt2 ----------------
// Wt2[n*400 + 2*(j%200) + j/200] = W_ih[j*360+n]
__global__ void transpose_wih(const float* __restrict__ Wih, float* __restrict__ Wt2) {
    int idx = blockIdx.x * blockDim.x + threadIdx.x;
    if (idx < NN * G4) {
        int j = idx / NN, n = idx % NN;
        Wt2[n * G4 + 2 * (j % 200) + (j / 200)] = Wih[idx];
    }
}

// ---------------- K2: xproj, no LDS ----------------
// 384 blocks x 256 thr (200 active). 4 bt-rows per block; g rows read as
// uniform-address global float4 (1 line/wave-inst, L2-hot); each thread
// covers cols (tid, tid+200) via one float2 of Wt2 (coalesced).
__global__ __launch_bounds__(256) void xproj_kernel(const float* __restrict__ gout,
                                                    const float* __restrict__ Wt2,
                                                    const float* __restrict__ b_ih,
                                                    const float* __restrict__ b_hh,
                                                    float* __restrict__ xproj) {
    int tid = threadIdx.x;
    if (tid >= 200) return;
    int r0 = blockIdx.x * 4;
    float acc00 = 0.f, acc01 = 0.f, acc10 = 0.f, acc11 = 0.f;
    float acc20 = 0.f, acc21 = 0.f, acc30 = 0.f, acc31 = 0.f;
    const float* g0p = gout + (size_t)(r0 + 0) * NN;
    const float* g1p = gout + (size_t)(r0 + 1) * NN;
    const float* g2p = gout + (size_t)(r0 + 2) * NN;
    const float* g3p = gout + (size_t)(r0 + 3) * NN;
    const float* wp = Wt2 + 2 * tid;
    for (int n = 0; n < NN; n += 4) {
        float4 g0 = *(const float4*)(g0p + n);
        float4 g1 = *(const float4*)(g1p + n);
        float4 g2 = *(const float4*)(g2p + n);
        float4 g3 = *(const float4*)(g3p + n);
        float2 wA = *(const float2*)(wp + (n + 0) * G4);
        float2 wB = *(const float2*)(wp + (n + 1) * G4);
        float2 wC = *(const float2*)(wp + (n + 2) * G4);
        float2 wD = *(const float2*)(wp + (n + 3) * G4);
        acc00 += g0.x*wA.x + g0.y*wB.x + g0.z*wC.x + g0.w*wD.x;
        acc01 += g0.x*wA.y + g0.y*wB.y + g0.z*wC.y + g0.w*wD.y;
        acc10 += g1.x*wA.x + g1.y*wB.x + g1.z*wC.x + g1.w*wD.x;
        acc11 += g1.x*wA.y + g1.y*wB.y + g1.z*wC.y + g1.w*wD.y;
        acc20 += g2.x*wA.x + g2.y*wB.x + g2.z*wC.x + g2.w*wD.x;
        acc21 += g2.x*wA.y + g2.y*wB.y + g2.z*wC.y + g2.w*wD.y;
        acc30 += g3.x*wA.x + g3.y*wB.x + g3.z*wC.x + g3.w*wD.x;
        acc31 += g3.x*wA.y + g3.y*wB.y + g3.z*wC.y + g3.w*wD.y;
    }
    float bias0 = b_ih[tid] + b_hh[tid];
    float bias1 = b_ih[tid + 200] + b_hh[tid + 200];
    xproj[(size_t)(r0 + 0) * G4 + tid]       = acc00 + bias0;
    xproj[(size_t)(r0 + 0) * G4 + tid + 200] = acc01 + bias1;
    xproj[(size_t)(r0 + 1) * G4 + tid]       = acc10 + bias0;
    xproj[(size_t)(r0 + 1) * G4 + tid + 200] = acc11 + bias1;
    xproj[(size_t)(r0 + 2) * G4 + tid]       = acc20 + bias0;
    xproj[(size_t)(r0 + 2) * G4 + tid + 200] = acc21 + bias1;
    xproj[(size_t)(r0 + 3) * G4 + tid]       = acc30 + bias0;
    xproj[(size_t)(r0 + 3) * G4 + tid + 200] = acc31 + bias1;
}

// ---------------- K3: fused LSTM + MIL attention + classifier ----------------
// Gate matvec via v_readlane SGPR broadcast of h (no LDS broadcast storm).
__global__ __launch_bounds__(448) void lstm_attn_kernel(const float* __restrict__ xproj,
                                                        const float* __restrict__ Whh,
                                                        const float* __restrict__ wa1,
                                                        const float* __restrict__ ba1,
                                                        const float* __restrict__ wa2,
                                                        const float* __restrict__ ba2,
                                                        const float* __restrict__ wc,
                                                        const float* __restrict__ bc,
                                                        float* __restrict__ out) {
    __shared__ __align__(16) float ho[TT * HH];    // 19.2 KB
    __shared__ __align__(16) float h_lds[128];     // 100 used; 100..127 stay 0
    __shared__ float gates[G4];
    __shared__ float sc[TT];
    __shared__ float p[TT];
    __shared__ float M[HH];
    int b = blockIdx.x;
    int tid = threadIdx.x;
    int lane = tid & 63;
    float wr[HH];
    if (tid < G4) {
        #pragma unroll
        for (int k = 0; k < HH; k++) wr[k] = Whh[tid * HH + k];
    }
    float c = 0.f;
    if (tid < 128) h_lds[tid] = 0.f;
    float xp = (tid < G4) ? xproj[(size_t)(b * TT) * G4 + tid] : 0.f;
    __syncthreads();
    for (int t = 0; t < TT; t++) {
        float xp_next = (tid < G4 && t + 1 < TT)
                      ? xproj[(size_t)(b * TT + t + 1) * G4 + tid] : 0.f;
        float ha = h_lds[lane];
        float hb = h_lds[64 + lane];
        if (tid < G4) {
            float s0 = 0.f, s1 = 0.f, s2 = 0.f, s3 = 0.f;
            #pragma unroll
            for (int k = 0; k < 64; k += 4) {
                s0 += bcast_lane(ha, k+0) * wr[k+0];
                s1 += bcast_lane(ha, k+1) * wr[k+1];
                s2 += bcast_lane(ha, k+2) * wr[k+2];
                s3 += bcast_lane(ha, k+3) * wr[k+3];
            }
            #pragma unroll
            for (int k = 64; k < 100; k += 4) {
                s0 += bcast_lane(hb, k-64) * wr[k+0];
                s1 += bcast_lane(hb, k-63) * wr[k+1];
                s2 += bcast_lane(hb, k-62) * wr[k+2];
                s3 += bcast_lane(hb, k-61) * wr[k+3];
            }
            gates[tid] = xp + (s0 + s1) + (s2 + s3);
        }
        __syncthreads();
        if (tid < HH) {
            float ig = sigmoid_fast(gates[tid]);
            float fg = sigmoid_fast(gates[tid + HH]);
            float gg = tanh_fast(gates[tid + 2*HH]);
            float og = sigmoid_fast(gates[tid + 3*HH]);
            c = fg * c + ig * gg;
            float hh = og * tanh_fast(c);
            h_lds[tid] = hh;
            ho[t * HH + tid] = hh;
        }
        xp = xp_next;
        __syncthreads();
    }
    // ---- MIL attention ----
    int wave = tid >> 6;
    for (int t = wave; t < TT; t += 7) {
        float a = 0.f;
        if (lane < DD) {
            float s = ba1[lane];
            #pragma unroll
            for (int h2 = 0; h2 < HH; h2 += 4) {
                float4 h4v = *(const float4*)&ho[t*HH + h2];
                s += wa1[lane*HH + h2+0]*h4v.x + wa1[lane*HH + h2+1]*h4v.y
                   + wa1[lane*HH + h2+2]*h4v.z + wa1[lane*HH + h2+3]*h4v.w;
            }
            a = tanh_fast(s) * wa2[lane];
        }
        #pragma unroll
        for (int off = 32; off; off >>= 1) a += __shfl_down(a, off, 64);
        if (lane == 0) sc[t] = a + ba2[0];
    }
    __syncthreads();
    if (tid < 64) {
        float v = (lane < TT) ? sc[lane] : -1e30f;
        if (lane < TT) out[BB*NC + b*TT + lane] = v;      // Att (pre-softmax logits)
        float m = v;
        #pragma unroll
        for (int off = 32; off; off >>= 1) m = fmaxf(m, __shfl_xor(m, off, 64));
        float e = (lane < TT) ? __expf(v - m) : 0.f;
        float s = e;
        #pragma unroll
        for (int off = 32; off; off >>= 1) s += __shfl_xor(s, off, 64);
        if (lane < TT) p[lane] = e / s;
    }
    __syncthreads();
    if (tid < HH) {
        float m = 0.f;
        #pragma unroll
        for (int t = 0; t < TT; t++) m += p[t] * ho[t*HH + tid];
        M[tid] = m;
    }
    __syncthreads();
    if (tid == 0) {
        float l0 = bc[0], l1 = bc[1];
        for (int h2 = 0; h2 < HH; h2++) { l0 += M[h2]*wc[h2]; l1 += M[h2]*wc[HH + h2]; }
        float mx = fmaxf(l0, l1);
        float e0 = __expf(l0 - mx), e1 = __expf(l1 - mx);
        float s = e0 + e1;
        out[b*NC + 0] = e0 / s;
        out[b*NC + 1] = e1 / s;
    }
}

extern "C" void kernel_launch(void* const* d_in, const int* in_sizes, int n_in,
                              void* d_out, int out_size, void* d_ws, size_t ws_size,
                              hipStream_t stream) {
    const float* x     = (const float*)d_in[0];
    const float* w_gcn = (const float*)d_in[1];
    const float* b_gcn = (const float*)d_in[2];
    const float* W_ih  = (const float*)d_in[3];
    const float* W_hh  = (const float*)d_in[4];
    const float* b_ih  = (const float*)d_in[5];
    const float* b_hh  = (const float*)d_in[6];
    const float* wa1   = (const float*)d_in[7];
    const float* ba1   = (const float*)d_in[8];
    const float* wa2   = (const float*)d_in[9];
    const float* ba2   = (const float*)d_in[10];
    const float* wc    = (const float*)d_in[11];
    const float* bc    = (const float*)d_in[12];
    float* out = (float*)d_out;
    float* ws  = (float*)d_ws;

    float* gout  = ws;                       // 552960 floats
    float* Wt2   = gout + 552960;            // 144000 floats
    float* xproj = Wt2 + 144000;             // 614400 floats

    int nquads = BB * TT * NN / 4;           // 138240
    transpose_wih<<<(NN*G4 + 255)/256, 256, 0, stream>>>(W_ih, Wt2);
    gcn_kernel<<<2048, 256, 0, stream>>>(x, w_gcn, b_gcn, gout, nquads);
    xproj_kernel<<<384, 256, 0, stream>>>(gout, Wt2, b_ih, b_hh, xproj);
    lstm_attn_kernel<<<BB, 448, 0, stream>>>(xproj, W_hh, wa1, ba1, wa2, ba2, wc, bc, out);
}

// Round 9
// 222.125 us; speedup vs baseline: 3.3065x; 1.0032x over previous
//
#include <hip/hip_runtime.h>
#include <math.h>

#define BB 32
#define TT 48
#define NN 360
#define HH 100
#define DD 64
#define NC 2
#define G4 400

typedef float vf4 __attribute__((ext_vector_type(4)));

__device__ __forceinline__ float sigmoid_fast(float x) {
    return 1.f / (1.f + __expf(-x));
}
__device__ __forceinline__ float tanh_fast(float x) {
    float ax = fabsf(x);
    float e = __expf(-2.f * ax);
    float t = (1.f - e) / (1.f + e);
    return copysignf(t, x);
}
__device__ __forceinline__ float dot4v(vf4 a, float4 b) {
    return a.x*b.x + a.y*b.y + a.z*b.z + a.w*b.w;
}
__device__ __forceinline__ float bcast_lane(float v, int l) {
    return __int_as_float(__builtin_amdgcn_readlane(__float_as_int(v), l));
}
__device__ __forceinline__ vf4 ntload4(const float* p) {
    return __builtin_nontemporal_load((const vf4*)p);
}

// Wave64 sum via DPP (VALU, no LDS pipe): row_shr 1/2/4/8 then row_bcast 15/31.
// Result valid in lane 63.
#define DPP_ADD(x, ctrl, rmask) \
    x += __int_as_float(__builtin_amdgcn_update_dpp(0, __float_as_int(x), ctrl, rmask, 0xf, true));
#define WAVE_RED(p) \
    DPP_ADD(p, 0x111, 0xf) DPP_ADD(p, 0x112, 0xf) DPP_ADD(p, 0x114, 0xf) DPP_ADD(p, 0x118, 0xf) \
    DPP_ADD(p, 0x142, 0xa) DPP_ADD(p, 0x143, 0xc)

// ---------------- K1: GCN row reduction, 4 rows/wave-iter, DPP reduce ----------------
__global__ __launch_bounds__(256) void gcn_kernel(const float* __restrict__ x,
                                                  const float* __restrict__ w,
                                                  const float* __restrict__ bptr,
                                                  float* __restrict__ gout, int nquads) {
    int tid = threadIdx.x;
    int lane = tid & 63;
    int wv = tid >> 6;                       // 0..3
    float4 wa = ((const float4*)w)[lane];
    float4 wb = (lane < 26) ? ((const float4*)w)[lane + 64] : make_float4(0.f, 0.f, 0.f, 0.f);
    float b = bptr[0];
    int stride = 4 * gridDim.x;
    for (int q = blockIdx.x * 4 + wv; q < nquads; q += stride) {
        int row0 = 4 * q;
        const float* x0 = x + (size_t)(row0 + 0) * NN;
        const float* x1 = x + (size_t)(row0 + 1) * NN;
        const float* x2 = x + (size_t)(row0 + 2) * NN;
        const float* x3 = x + (size_t)(row0 + 3) * NN;
        vf4 a0 = ntload4(x0 + 4*lane);
        vf4 a1 = ntload4(x1 + 4*lane);
        vf4 a2 = ntload4(x2 + 4*lane);
        vf4 a3 = ntload4(x3 + 4*lane);
        float p0 = dot4v(a0, wa);
        float p1 = dot4v(a1, wa);
        float p2 = dot4v(a2, wa);
        float p3 = dot4v(a3, wa);
        if (lane < 26) {                     // 90 = 64 + 26
            vf4 b0 = ntload4(x0 + 4*(lane + 64));
            vf4 b1 = ntload4(x1 + 4*(lane + 64));
            vf4 b2 = ntload4(x2 + 4*(lane + 64));
            vf4 b3 = ntload4(x3 + 4*(lane + 64));
            p0 += dot4v(b0, wb);
            p1 += dot4v(b1, wb);
            p2 += dot4v(b2, wb);
            p3 += dot4v(b3, wb);
        }
        WAVE_RED(p0)
        WAVE_RED(p1)
        WAVE_RED(p2)
        WAVE_RED(p3)
        if (lane == 63) {
            float4 r;
            r.x = fmaxf(p0 + b, 0.f);
            r.y = fmaxf(p1 + b, 0.f);
            r.z = fmaxf(p2 + b, 0.f);
            r.w = fmaxf(p3 + b, 0.f);
            ((float4*)gout)[q] = r;
        }
    }
}

// ---------------- K2a: transpose W_ih [400,360] -> pair-interleaved Wt2 ----------------
// Wt2[n*400 + 2*(j%200) + j/200] = W_ih[j*360+n]
__global__ void transpose_wih(const float* __restrict__ Wih, float* __restrict__ Wt2) {
    int idx = blockIdx.x * blockDim.x + threadIdx.x;
    if (idx < NN * G4) {
        int j = idx / NN, n = idx % NN;
        Wt2[n * G4 + 2 * (j % 200) + (j / 200)] = Wih[idx];
    }
}

// ---------------- K2: xproj, no LDS ----------------
__global__ __launch_bounds__(256) void xproj_kernel(const float* __restrict__ gout,
                                                    const float* __restrict__ Wt2,
                                                    const float* __restrict__ b_ih,
                                                    const float* __restrict__ b_hh,
                                                    float* __restrict__ xproj) {
    int tid = threadIdx.x;
    if (tid >= 200) return;
    int r0 = blockIdx.x * 4;
    float acc00 = 0.f, acc01 = 0.f, acc10 = 0.f, acc11 = 0.f;
    float acc20 = 0.f, acc21 = 0.f, acc30 = 0.f, acc31 = 0.f;
    const float* g0p = gout + (size_t)(r0 + 0) * NN;
    const float* g1p = gout + (size_t)(r0 + 1) * NN;
    const float* g2p = gout + (size_t)(r0 + 2) * NN;
    const float* g3p = gout + (size_t)(r0 + 3) * NN;
    const float* wp = Wt2 + 2 * tid;
    for (int n = 0; n < NN; n += 4) {
        float4 g0 = *(const float4*)(g0p + n);
        float4 g1 = *(const float4*)(g1p + n);
        float4 g2 = *(const float4*)(g2p + n);
        float4 g3 = *(const float4*)(g3p + n);
        float2 wA = *(const float2*)(wp + (n + 0) * G4);
        float2 wB = *(const float2*)(wp + (n + 1) * G4);
        float2 wC = *(const float2*)(wp + (n + 2) * G4);
        float2 wD = *(const float2*)(wp + (n + 3) * G4);
        acc00 += g0.x*wA.x + g0.y*wB.x + g0.z*wC.x + g0.w*wD.x;
        acc01 += g0.x*wA.y + g0.y*wB.y + g0.z*wC.y + g0.w*wD.y;
        acc10 += g1.x*wA.x + g1.y*wB.x + g1.z*wC.x + g1.w*wD.x;
        acc11 += g1.x*wA.y + g1.y*wB.y + g1.z*wC.y + g1.w*wD.y;
        acc20 += g2.x*wA.x + g2.y*wB.x + g2.z*wC.x + g2.w*wD.x;
        acc21 += g2.x*wA.y + g2.y*wB.y + g2.z*wC.y + g2.w*wD.y;
        acc30 += g3.x*wA.x + g3.y*wB.x + g3.z*wC.x + g3.w*wD.x;
        acc31 += g3.x*wA.y + g3.y*wB.y + g3.z*wC.y + g3.w*wD.y;
    }
    float bias0 = b_ih[tid] + b_hh[tid];
    float bias1 = b_ih[tid + 200] + b_hh[tid + 200];
    xproj[(size_t)(r0 + 0) * G4 + tid]       = acc00 + bias0;
    xproj[(size_t)(r0 + 0) * G4 + tid + 200] = acc01 + bias1;
    xproj[(size_t)(r0 + 1) * G4 + tid]       = acc10 + bias0;
    xproj[(size_t)(r0 + 1) * G4 + tid + 200] = acc11 + bias1;
    xproj[(size_t)(r0 + 2) * G4 + tid]       = acc20 + bias0;
    xproj[(size_t)(r0 + 2) * G4 + tid + 200] = acc21 + bias1;
    xproj[(size_t)(r0 + 3) * G4 + tid]       = acc30 + bias0;
    xproj[(size_t)(r0 + 3) * G4 + tid + 200] = acc31 + bias1;
}

// ---------------- K3: fused LSTM + MIL attention + classifier ----------------
__global__ __launch_bounds__(448) void lstm_attn_kernel(const float* __restrict__ xproj,
                                                        const float* __restrict__ Whh,
                                                        const float* __restrict__ wa1,
                                                        const float* __restrict__ ba1,
                                                        const float* __restrict__ wa2,
                                                        const float* __restrict__ ba2,
                                                        const float* __restrict__ wc,
                                                        const float* __restrict__ bc,
                                                        float* __restrict__ out) {
    __shared__ __align__(16) float ho[TT * HH];    // 19.2 KB
    __shared__ __align__(16) float h_lds[128];     // 100 used; 100..127 stay 0
    __shared__ float gates[G4];
    __shared__ float sc[TT];
    __shared__ float p[TT];
    __shared__ float M[HH];
    int b = blockIdx.x;
    int tid = threadIdx.x;
    int lane = tid & 63;
    float wr[HH];
    if (tid < G4) {
        #pragma unroll
        for (int k = 0; k < HH; k++) wr[k] = Whh[tid * HH + k];
    }
    float c = 0.f;
    if (tid < 128) h_lds[tid] = 0.f;
    float xp = (tid < G4) ? xproj[(size_t)(b * TT) * G4 + tid] : 0.f;
    __syncthreads();
    for (int t = 0; t < TT; t++) {
        float xp_next = (tid < G4 && t + 1 < TT)
                      ? xproj[(size_t)(b * TT + t + 1) * G4 + tid] : 0.f;
        float ha = h_lds[lane];
        float hb = h_lds[64 + lane];
        if (tid < G4) {
            float s0 = 0.f, s1 = 0.f, s2 = 0.f, s3 = 0.f;
            #pragma unroll
            for (int k = 0; k < 64; k += 4) {
                s0 += bcast_lane(ha, k+0) * wr[k+0];
                s1 += bcast_lane(ha, k+1) * wr[k+1];
                s2 += bcast_lane(ha, k+2) * wr[k+2];
                s3 += bcast_lane(ha, k+3) * wr[k+3];
            }
            #pragma unroll
            for (int k = 64; k < 100; k += 4) {
                s0 += bcast_lane(hb, k-64) * wr[k+0];
                s1 += bcast_lane(hb, k-63) * wr[k+1];
                s2 += bcast_lane(hb, k-62) * wr[k+2];
                s3 += bcast_lane(hb, k-61) * wr[k+3];
            }
            gates[tid] = xp + (s0 + s1) + (s2 + s3);
        }
        __syncthreads();
        if (tid < HH) {
            float ig = sigmoid_fast(gates[tid]);
            float fg = sigmoid_fast(gates[tid + HH]);
            float gg = tanh_fast(gates[tid + 2*HH]);
            float og = sigmoid_fast(gates[tid + 3*HH]);
            c = fg * c + ig * gg;
            float hh = og * tanh_fast(c);
            h_lds[tid] = hh;
            ho[t * HH + tid] = hh;
        }
        xp = xp_next;
        __syncthreads();
    }
    // ---- MIL attention ----
    int wave = tid >> 6;
    for (int t = wave; t < TT; t += 7) {
        float a = 0.f;
        if (lane < DD) {
            float s = ba1[lane];
            #pragma unroll
            for (int h2 = 0; h2 < HH; h2 += 4) {
                float4 h4v = *(const float4*)&ho[t*HH + h2];
                s += wa1[lane*HH + h2+0]*h4v.x + wa1[lane*HH + h2+1]*h4v.y
                   + wa1[lane*HH + h2+2]*h4v.z + wa1[lane*HH + h2+3]*h4v.w;
            }
            a = tanh_fast(s) * wa2[lane];
        }
        #pragma unroll
        for (int off = 32; off; off >>= 1) a += __shfl_down(a, off, 64);
        if (lane == 0) sc[t] = a + ba2[0];
    }
    __syncthreads();
    if (tid < 64) {
        float v = (lane < TT) ? sc[lane] : -1e30f;
        if (lane < TT) out[BB*NC + b*TT + lane] = v;      // Att (pre-softmax logits)
        float m = v;
        #pragma unroll
        for (int off = 32; off; off >>= 1) m = fmaxf(m, __shfl_xor(m, off, 64));
        float e = (lane < TT) ? __expf(v - m) : 0.f;
        float s = e;
        #pragma unroll
        for (int off = 32; off; off >>= 1) s += __shfl_xor(s, off, 64);
        if (lane < TT) p[lane] = e / s;
    }
    __syncthreads();
    if (tid < HH) {
        float m = 0.f;
        #pragma unroll
        for (int t = 0; t < TT; t++) m += p[t] * ho[t*HH + tid];
        M[tid] = m;
    }
    __syncthreads();
    if (tid == 0) {
        float l0 = bc[0], l1 = bc[1];
        for (int h2 = 0; h2 < HH; h2++) { l0 += M[h2]*wc[h2]; l1 += M[h2]*wc[HH + h2]; }
        float mx = fmaxf(l0, l1);
        float e0 = __expf(l0 - mx), e1 = __expf(l1 - mx);
        float s = e0 + e1;
        out[b*NC + 0] = e0 / s;
        out[b*NC + 1] = e1 / s;
    }
}

extern "C" void kernel_launch(void* const* d_in, const int* in_sizes, int n_in,
                              void* d_out, int out_size, void* d_ws, size_t ws_size,
                              hipStream_t stream) {
    const float* x     = (const float*)d_in[0];
    const float* w_gcn = (const float*)d_in[1];
    const float* b_gcn = (const float*)d_in[2];
    const float* W_ih  = (const float*)d_in[3];
    const float* W_hh  = (const float*)d_in[4];
    const float* b_ih  = (const float*)d_in[5];
    const float* b_hh  = (const float*)d_in[6];
    const float* wa1   = (const float*)d_in[7];
    const float* ba1   = (const float*)d_in[8];
    const float* wa2   = (const float*)d_in[9];
    const float* ba2   = (const float*)d_in[10];
    const float* wc    = (const float*)d_in[11];
    const float* bc    = (const float*)d_in[12];
    float* out = (float*)d_out;
    float* ws  = (float*)d_ws;

    float* gout  = ws;                       // 552960 floats
    float* Wt2   = gout + 552960;            // 144000 floats
    float* xproj = Wt2 + 144000;             // 614400 floats

    int nquads = BB * TT * NN / 4;           // 138240
    transpose_wih<<<(NN*G4 + 255)/256, 256, 0, stream>>>(W_ih, Wt2);
    gcn_kernel<<<2048, 256, 0, stream>>>(x, w_gcn, b_gcn, gout, nquads);
    xproj_kernel<<<384, 256, 0, stream>>>(gout, Wt2, b_ih, b_hh, xproj);
    lstm_attn_kernel<<<BB, 448, 0, stream>>>(xproj, W_hh, wa1, ba1, wa2, ba2, wc, bc, out);
}